// Round 1
// baseline (53171.777 us; speedup 1.0000x reference)
//
#include <hip/hip_runtime.h>
#include <cstddef>
#include <cstdint>

#define NN  100000
#define EE  1000000
#define CIN 256
#define HD  128
#define HF  64

// ---------------- counting / inverse ----------------
__global__ __launch_bounds__(256) void k_count(const int* __restrict__ pos,
                                               const int* __restrict__ neg,
                                               float* __restrict__ cp,
                                               float* __restrict__ cn) {
  int i = blockIdx.x * 256 + threadIdx.x;
  if (i < EE) {
    unsafeAtomicAdd(&cp[pos[EE + i]], 1.0f);
    unsafeAtomicAdd(&cn[neg[EE + i]], 1.0f);
  }
}

__global__ __launch_bounds__(256) void k_inv(float* __restrict__ a, float* __restrict__ b) {
  int i = blockIdx.x * 256 + threadIdx.x;
  if (i < NN) {
    a[i] = 1.0f / fmaxf(a[i], 1.0f);
    b[i] = 1.0f / fmaxf(b[i], 1.0f);
  }
}

// ---------------- scatter-add (sum aggregation) ----------------
// 32 threads per edge, float4 per thread: coalesced 512B row gather,
// 4 f32 atomics per thread into the destination row.
__global__ __launch_bounds__(256) void k_scatter(const float* __restrict__ feat,
                                                 const int* __restrict__ ei,
                                                 float* out) {
  long long gid = (long long)blockIdx.x * 256 + threadIdx.x;
  int e = (int)(gid >> 5);
  int lane = (int)(gid & 31);
  if (e >= EE) return;
  int src = ei[e];
  int dst = ei[EE + e];
  const float4 v = *reinterpret_cast<const float4*>(feat + (size_t)src * HD + lane * 4);
  float* o = out + (size_t)dst * HD + lane * 4;
  unsafeAtomicAdd(o + 0, v.x);
  unsafeAtomicAdd(o + 1, v.y);
  unsafeAtomicAdd(o + 2, v.z);
  unsafeAtomicAdd(o + 3, v.w);
}

// ---------------- build fused weight matrices ----------------
// Layer1: A = [aggP(128) | h(128) | aggN(128)], out = A @ Wbig + bias
__global__ __launch_bounds__(256) void k_build_w1(const float* __restrict__ Wpl, const float* __restrict__ Wpr,
                                                  const float* __restrict__ Wnl, const float* __restrict__ Wnr,
                                                  const float* __restrict__ bp, const float* __restrict__ bn,
                                                  float* __restrict__ Wbig, float* __restrict__ bias) {
  int idx = blockIdx.x * 256 + threadIdx.x;
  if (idx < HD) bias[idx] = (idx < HF) ? bp[idx] : bn[idx - HF];
  if (idx >= 384 * HD) return;
  int k = idx >> 7, j = idx & 127;
  float v = 0.0f;
  if (k < 128)      { if (j <  HF) v = Wpl[k * HF + j]; }
  else if (k < 256) { v = (j < HF) ? Wpr[(k - 128) * HF + j] : Wnr[(k - 128) * HF + (j - HF)]; }
  else              { if (j >= HF) v = Wnl[(k - 256) * HF + (j - HF)]; }
  Wbig[idx] = v;
}

// Layer2: A = [sumP2*invp (128) | sumN2*invn (128) | z (128)]
//   k   0.. 63: mean(zp,pos) -> out_p via W2pl[0:64]
//   k  64..127: mean(zn,pos) -> out_n via W2nl[0:64]
//   k 128..191: mean(zp,neg) -> out_n via W2nl[64:128]
//   k 192..255: mean(zn,neg) -> out_p via W2pl[64:128]
//   k 256..319: zp           -> out_p via W2pr
//   k 320..383: zn           -> out_n via W2nr
__global__ __launch_bounds__(256) void k_build_w2(const float* __restrict__ Wpl, const float* __restrict__ Wpr,
                                                  const float* __restrict__ Wnl, const float* __restrict__ Wnr,
                                                  const float* __restrict__ bp, const float* __restrict__ bn,
                                                  float* __restrict__ Wbig, float* __restrict__ bias) {
  int idx = blockIdx.x * 256 + threadIdx.x;
  if (idx < HD) bias[idx] = (idx < HF) ? bp[idx] : bn[idx - HF];
  if (idx >= 384 * HD) return;
  int k = idx >> 7, j = idx & 127;
  float v = 0.0f;
  if (k < 64)       { if (j <  HF) v = Wpl[k * HF + j]; }
  else if (k < 128) { if (j >= HF) v = Wnl[(k - 64) * HF + (j - HF)]; }
  else if (k < 192) { if (j >= HF) v = Wnl[(k - 128 + 64) * HF + (j - HF)]; }
  else if (k < 256) { if (j <  HF) v = Wpl[(k - 192 + 64) * HF + j]; }
  else if (k < 320) { if (j <  HF) v = Wpr[(k - 256) * HF + j]; }
  else              { if (j >= HF) v = Wnr[(k - 320) * HF + (j - HF)]; }
  Wbig[idx] = v;
}

// ---------------- fused tiled GEMM: out = relu?(gather(A)@W + bias) ----------------
// A gathered from up to 3 sources of width SRCW each, optional per-row scale.
// BM=64 rows/block, BK=32, full Nout=128. 256 threads: 16x16, each 4 rows x 8 cols.
template <int KTOT, int SRCW, bool RELU>
__global__ __launch_bounds__(256) void k_gemm(const float* A0, const float* A1, const float* A2,
                                              const float* __restrict__ s0, const float* __restrict__ s1,
                                              const float* __restrict__ s2,
                                              const float* __restrict__ W, const float* __restrict__ bias,
                                              float* out, int nrows) {
  constexpr int BM = 64, BK = 32, NCH = KTOT / BK;
  __shared__ float As[BK][BM + 4];   // transposed: As[k][row], padded for b128 alignment
  __shared__ float Ws[BK][HD];

  const int tid = threadIdx.x;
  const int sr = tid >> 2;            // A-stage row 0..63
  const int scb = (tid & 3) * 8;      // A-stage col base {0,8,16,24}
  const int srow = blockIdx.x * BM + sr;
  const bool srok = srow < nrows;

  const int wk = tid >> 3;            // W-stage k 0..31
  const int wc = (tid & 7) * 16;      // W-stage col base

  const int tm = tid >> 4;            // 0..15 -> rows tm*4..tm*4+3
  const int tn = tid & 15;            // 0..15 -> cols tn*8..tn*8+7

  float acc[4][8];
#pragma unroll
  for (int i = 0; i < 4; i++)
#pragma unroll
    for (int j = 0; j < 8; j++) acc[i][j] = 0.0f;

#pragma unroll
  for (int c = 0; c < NCH; c++) {
    const int col0 = c * BK;
    const int s = col0 / SRCW;        // constant after unroll
    const int lc = col0 % SRCW;
    const float* Ap = (s == 0) ? A0 : ((s == 1) ? A1 : A2);
    const float* Sp = (s == 0) ? s0 : ((s == 1) ? s1 : s2);

    __syncthreads();
    // stage A chunk (64 rows x 32 cols), scaled
    float4 v0 = make_float4(0.f, 0.f, 0.f, 0.f), v1 = v0;
    if (srok) {
      const float* base = Ap + (size_t)srow * SRCW + lc + scb;
      v0 = *reinterpret_cast<const float4*>(base);
      v1 = *reinterpret_cast<const float4*>(base + 4);
      if (Sp) {
        const float sc = Sp[srow];
        v0.x *= sc; v0.y *= sc; v0.z *= sc; v0.w *= sc;
        v1.x *= sc; v1.y *= sc; v1.z *= sc; v1.w *= sc;
      }
    }
    As[scb + 0][sr] = v0.x; As[scb + 1][sr] = v0.y;
    As[scb + 2][sr] = v0.z; As[scb + 3][sr] = v0.w;
    As[scb + 4][sr] = v1.x; As[scb + 5][sr] = v1.y;
    As[scb + 6][sr] = v1.z; As[scb + 7][sr] = v1.w;

    // stage W chunk (32 x 128)
    {
      const float* wb = W + (size_t)(col0 + wk) * HD + wc;
      float4 w0 = *reinterpret_cast<const float4*>(wb + 0);
      float4 w1 = *reinterpret_cast<const float4*>(wb + 4);
      float4 w2 = *reinterpret_cast<const float4*>(wb + 8);
      float4 w3 = *reinterpret_cast<const float4*>(wb + 12);
      *reinterpret_cast<float4*>(&Ws[wk][wc + 0])  = w0;
      *reinterpret_cast<float4*>(&Ws[wk][wc + 4])  = w1;
      *reinterpret_cast<float4*>(&Ws[wk][wc + 8])  = w2;
      *reinterpret_cast<float4*>(&Ws[wk][wc + 12]) = w3;
    }
    __syncthreads();

#pragma unroll
    for (int k = 0; k < BK; k++) {
      const float4 a4 = *reinterpret_cast<const float4*>(&As[k][tm * 4]);
      const float4 b0 = *reinterpret_cast<const float4*>(&Ws[k][tn * 8]);
      const float4 b1 = *reinterpret_cast<const float4*>(&Ws[k][tn * 8 + 4]);
      const float a[4] = {a4.x, a4.y, a4.z, a4.w};
      const float b[8] = {b0.x, b0.y, b0.z, b0.w, b1.x, b1.y, b1.z, b1.w};
#pragma unroll
      for (int i = 0; i < 4; i++)
#pragma unroll
        for (int j = 0; j < 8; j++) acc[i][j] = fmaf(a[i], b[j], acc[i][j]);
    }
  }

  const float4 bb0 = *reinterpret_cast<const float4*>(&bias[tn * 8]);
  const float4 bb1 = *reinterpret_cast<const float4*>(&bias[tn * 8 + 4]);
  const float bb[8] = {bb0.x, bb0.y, bb0.z, bb0.w, bb1.x, bb1.y, bb1.z, bb1.w};
#pragma unroll
  for (int i = 0; i < 4; i++) {
    const int row = blockIdx.x * BM + tm * 4 + i;
    if (row < nrows) {
      float o[8];
#pragma unroll
      for (int j = 0; j < 8; j++) {
        float v = acc[i][j] + bb[j];
        o[j] = RELU ? fmaxf(v, 0.0f) : v;
      }
      float4* dst = reinterpret_cast<float4*>(out + (size_t)row * HD + tn * 8);
      dst[0] = make_float4(o[0], o[1], o[2], o[3]);
      dst[1] = make_float4(o[4], o[5], o[6], o[7]);
    }
  }
}

extern "C" void kernel_launch(void* const* d_in, const int* in_sizes, int n_in,
                              void* d_out, int out_size, void* d_ws, size_t ws_size,
                              hipStream_t stream) {
  const float* x    = (const float*)d_in[0];
  const int*   pos  = (const int*)d_in[1];
  const int*   neg  = (const int*)d_in[2];
  const float* W_in = (const float*)d_in[3];
  const float* b_in = (const float*)d_in[4];
  const float* W1pl = (const float*)d_in[5];
  const float* W1pr = (const float*)d_in[6];
  const float* b1p  = (const float*)d_in[7];
  const float* W1nl = (const float*)d_in[8];
  const float* W1nr = (const float*)d_in[9];
  const float* b1n  = (const float*)d_in[10];
  const float* W2pl = (const float*)d_in[11];
  const float* W2pr = (const float*)d_in[12];
  const float* b2p  = (const float*)d_in[13];
  const float* W2nl = (const float*)d_in[14];
  const float* W2nr = (const float*)d_in[15];
  const float* b2n  = (const float*)d_in[16];

  float* ws = (float*)d_ws;
  const size_t FM = (size_t)NN * HD;
  float* h    = ws;
  float* sumP = h + FM;
  float* sumN = sumP + FM;
  float* invp = sumN + FM;
  float* invn = invp + NN;
  float* Wb1  = invn + NN;
  float* Wb2  = Wb1 + 384 * HD;
  float* bi1  = Wb2 + 384 * HD;
  float* bi2  = bi1 + HD;
  float* wend = bi2 + HD;

  // z goes in ws if it fits, else aliases d_out (safe: combine2 reads its own
  // rows into LDS before its epilogue writes them, rows disjoint across blocks)
  float* z;
  const size_t need_with_z = ((size_t)(wend - ws) + FM) * sizeof(float);
  z = (ws_size >= need_with_z) ? wend : (float*)d_out;

  const size_t FMB = FM * sizeof(float);
  hipMemsetAsync(sumP, 0, FMB, stream);
  hipMemsetAsync(sumN, 0, FMB, stream);
  hipMemsetAsync(invp, 0, (size_t)NN * sizeof(float), stream);
  hipMemsetAsync(invn, 0, (size_t)NN * sizeof(float), stream);

  k_count<<<(EE + 255) / 256, 256, 0, stream>>>(pos, neg, invp, invn);
  k_inv<<<(NN + 255) / 256, 256, 0, stream>>>(invp, invn);
  k_build_w1<<<192, 256, 0, stream>>>(W1pl, W1pr, W1nl, W1nr, b1p, b1n, Wb1, bi1);
  k_build_w2<<<192, 256, 0, stream>>>(W2pl, W2pr, W2nl, W2nr, b2p, b2n, Wb2, bi2);

  const int gemm_grid = (NN + 63) / 64;
  k_gemm<CIN, CIN, false><<<gemm_grid, 256, 0, stream>>>(
      x, nullptr, nullptr, nullptr, nullptr, nullptr, W_in, b_in, h, NN);

  const int sc_grid = (EE * 32) / 256;  // 32 threads/edge
  k_scatter<<<sc_grid, 256, 0, stream>>>(h, pos, sumP);
  k_scatter<<<sc_grid, 256, 0, stream>>>(h, neg, sumN);

  k_gemm<384, HD, true><<<gemm_grid, 256, 0, stream>>>(
      sumP, h, sumN, invp, nullptr, invn, Wb1, bi1, z, NN);

  hipMemsetAsync(sumP, 0, FMB, stream);
  hipMemsetAsync(sumN, 0, FMB, stream);
  k_scatter<<<sc_grid, 256, 0, stream>>>(z, pos, sumP);
  k_scatter<<<sc_grid, 256, 0, stream>>>(z, neg, sumN);

  k_gemm<384, HD, true><<<gemm_grid, 256, 0, stream>>>(
      sumP, sumN, z, invp, invn, nullptr, Wb2, bi2, (float*)d_out, NN);
}

// Round 2
// 929.492 us; speedup vs baseline: 57.2052x; 57.2052x over previous
//
#include <hip/hip_runtime.h>
#include <cstddef>
#include <cstdint>

#define NN  100000
#define EE  1000000
#define CIN 256
#define HD  128
#define HF  64
#define SB  1024

// ---------------- degree count ----------------
__global__ __launch_bounds__(256) void k_deg(const int* __restrict__ pos,
                                             const int* __restrict__ neg,
                                             int* __restrict__ dp,
                                             int* __restrict__ dn) {
  int i = blockIdx.x * 256 + threadIdx.x;
  if (i < EE) {
    atomicAdd(&dp[pos[EE + i]], 1);
    atomicAdd(&dn[neg[EE + i]], 1);
  }
}

// ---------------- exclusive scan (3 kernels) ----------------
__global__ __launch_bounds__(SB) void k_scan1(const int* __restrict__ deg,
                                              int* __restrict__ off,
                                              int* __restrict__ bsum, int n) {
  __shared__ int s[SB];
  int i = blockIdx.x * SB + threadIdx.x;
  int v = (i < n) ? deg[i] : 0;
  s[threadIdx.x] = v;
  __syncthreads();
  for (int d = 1; d < SB; d <<= 1) {
    int t = (threadIdx.x >= d) ? s[threadIdx.x - d] : 0;
    __syncthreads();
    s[threadIdx.x] += t;
    __syncthreads();
  }
  if (i < n) off[i] = s[threadIdx.x] - v;  // exclusive
  if (threadIdx.x == SB - 1) bsum[blockIdx.x] = s[SB - 1];
}

__global__ __launch_bounds__(256) void k_scan2(int* __restrict__ bsum, int nb) {
  __shared__ int s[256];
  int v = (threadIdx.x < nb) ? bsum[threadIdx.x] : 0;
  s[threadIdx.x] = v;
  __syncthreads();
  for (int d = 1; d < 256; d <<= 1) {
    int t = (threadIdx.x >= d) ? s[threadIdx.x - d] : 0;
    __syncthreads();
    s[threadIdx.x] += t;
    __syncthreads();
  }
  if (threadIdx.x < nb) bsum[threadIdx.x] = s[threadIdx.x] - v;  // exclusive
}

__global__ __launch_bounds__(SB) void k_scan3(int* __restrict__ off,
                                              const int* __restrict__ bsum, int n) {
  int i = blockIdx.x * SB + threadIdx.x;
  if (i < n) off[i] += bsum[blockIdx.x];
}

// ---------------- CSR fill ----------------
__global__ __launch_bounds__(256) void k_fill(const int* __restrict__ ei,
                                              int* __restrict__ cur,
                                              int* __restrict__ csr) {
  int e = blockIdx.x * 256 + threadIdx.x;
  if (e < EE) {
    int dst = ei[EE + e];
    int p = atomicAdd(&cur[dst], 1);
    csr[p] = ei[e];
  }
}

// ---------------- gather mean-aggregate: one wave per node ----------------
__global__ __launch_bounds__(256) void k_gather(const float* __restrict__ feat,
                                                const int* __restrict__ off,
                                                const int* __restrict__ deg,
                                                const int* __restrict__ csr,
                                                float* __restrict__ out) {
  int wid = threadIdx.x >> 6, lane = threadIdx.x & 63;
  int node = blockIdx.x * 4 + wid;
  if (node >= NN) return;
  int start = off[node], d = deg[node];
  float2 acc = make_float2(0.f, 0.f);
  int k = 0;
  for (; k + 4 <= d; k += 4) {
    int s0 = csr[start + k], s1 = csr[start + k + 1];
    int s2 = csr[start + k + 2], s3 = csr[start + k + 3];
    const float2 a0 = *reinterpret_cast<const float2*>(feat + (size_t)s0 * HD + lane * 2);
    const float2 a1 = *reinterpret_cast<const float2*>(feat + (size_t)s1 * HD + lane * 2);
    const float2 a2 = *reinterpret_cast<const float2*>(feat + (size_t)s2 * HD + lane * 2);
    const float2 a3 = *reinterpret_cast<const float2*>(feat + (size_t)s3 * HD + lane * 2);
    acc.x += (a0.x + a1.x) + (a2.x + a3.x);
    acc.y += (a0.y + a1.y) + (a2.y + a3.y);
  }
  for (; k < d; k++) {
    int s0 = csr[start + k];
    const float2 a0 = *reinterpret_cast<const float2*>(feat + (size_t)s0 * HD + lane * 2);
    acc.x += a0.x;
    acc.y += a0.y;
  }
  float sc = 1.0f / fmaxf((float)d, 1.0f);
  *reinterpret_cast<float2*>(out + (size_t)node * HD + lane * 2) =
      make_float2(acc.x * sc, acc.y * sc);
}

// ---------------- build fused weight matrices (validated round 0) ----------------
__global__ __launch_bounds__(256) void k_build_w1(const float* __restrict__ Wpl, const float* __restrict__ Wpr,
                                                  const float* __restrict__ Wnl, const float* __restrict__ Wnr,
                                                  const float* __restrict__ bp, const float* __restrict__ bn,
                                                  float* __restrict__ Wbig, float* __restrict__ bias) {
  int idx = blockIdx.x * 256 + threadIdx.x;
  if (idx < HD) bias[idx] = (idx < HF) ? bp[idx] : bn[idx - HF];
  if (idx >= 384 * HD) return;
  int k = idx >> 7, j = idx & 127;
  float v = 0.0f;
  if (k < 128)      { if (j <  HF) v = Wpl[k * HF + j]; }
  else if (k < 256) { v = (j < HF) ? Wpr[(k - 128) * HF + j] : Wnr[(k - 128) * HF + (j - HF)]; }
  else              { if (j >= HF) v = Wnl[(k - 256) * HF + (j - HF)]; }
  Wbig[idx] = v;
}

__global__ __launch_bounds__(256) void k_build_w2(const float* __restrict__ Wpl, const float* __restrict__ Wpr,
                                                  const float* __restrict__ Wnl, const float* __restrict__ Wnr,
                                                  const float* __restrict__ bp, const float* __restrict__ bn,
                                                  float* __restrict__ Wbig, float* __restrict__ bias) {
  int idx = blockIdx.x * 256 + threadIdx.x;
  if (idx < HD) bias[idx] = (idx < HF) ? bp[idx] : bn[idx - HF];
  if (idx >= 384 * HD) return;
  int k = idx >> 7, j = idx & 127;
  float v = 0.0f;
  if (k < 64)       { if (j <  HF) v = Wpl[k * HF + j]; }
  else if (k < 128) { if (j >= HF) v = Wnl[(k - 64) * HF + (j - HF)]; }
  else if (k < 192) { if (j >= HF) v = Wnl[(k - 128 + 64) * HF + (j - HF)]; }
  else if (k < 256) { if (j <  HF) v = Wpl[(k - 192 + 64) * HF + j]; }
  else if (k < 320) { if (j <  HF) v = Wpr[(k - 256) * HF + j]; }
  else              { if (j >= HF) v = Wnr[(k - 320) * HF + (j - HF)]; }
  Wbig[idx] = v;
}

// ---------------- fused tiled GEMM: out = relu?(gather(A)@W + bias) ----------------
// BM=64 rows/block, BK=32, Nout=128. 256 threads: 16x16, each 4 rows x 8 cols.
// #pragma unroll 1 on the chunk loop: round-0 full unroll hoisted 12 chunks of
// staging loads -> 256 VGPR + scratch spills (21.6 GB FETCH, VALUBusy 0.8%).
template <int KTOT, int SRCW, bool RELU>
__global__ __launch_bounds__(256, 4) void k_gemm(const float* A0, const float* A1, const float* A2,
                                                 const float* __restrict__ W, const float* __restrict__ bias,
                                                 float* out, int nrows) {
  constexpr int BM = 64, BK = 32, NCH = KTOT / BK;
  __shared__ float As[BK][BM + 4];   // transposed: As[k][row]
  __shared__ float Ws[BK][HD];

  const int tid = threadIdx.x;
  const int sr = tid >> 2;            // A-stage row 0..63
  const int scb = (tid & 3) * 8;      // A-stage col base {0,8,16,24}
  const int srow = blockIdx.x * BM + sr;
  const bool srok = srow < nrows;

  const int wk = tid >> 3;            // W-stage k 0..31
  const int wc = (tid & 7) * 16;      // W-stage col base

  const int tm = tid >> 4;            // rows tm*4..tm*4+3
  const int tn = tid & 15;            // cols tn*8..tn*8+7

  float acc[4][8];
#pragma unroll
  for (int i = 0; i < 4; i++)
#pragma unroll
    for (int j = 0; j < 8; j++) acc[i][j] = 0.0f;

#pragma unroll 1
  for (int c = 0; c < NCH; c++) {
    const int col0 = c * BK;
    const int s = col0 / SRCW;
    const int lc = col0 % SRCW;
    const float* Ap = (s == 0) ? A0 : ((s == 1) ? A1 : A2);

    __syncthreads();
    float4 v0 = make_float4(0.f, 0.f, 0.f, 0.f), v1 = v0;
    if (srok) {
      const float* base = Ap + (size_t)srow * SRCW + lc + scb;
      v0 = *reinterpret_cast<const float4*>(base);
      v1 = *reinterpret_cast<const float4*>(base + 4);
    }
    As[scb + 0][sr] = v0.x; As[scb + 1][sr] = v0.y;
    As[scb + 2][sr] = v0.z; As[scb + 3][sr] = v0.w;
    As[scb + 4][sr] = v1.x; As[scb + 5][sr] = v1.y;
    As[scb + 6][sr] = v1.z; As[scb + 7][sr] = v1.w;

    {
      const float* wb = W + (size_t)(col0 + wk) * HD + wc;
      float4 w0 = *reinterpret_cast<const float4*>(wb + 0);
      float4 w1 = *reinterpret_cast<const float4*>(wb + 4);
      float4 w2 = *reinterpret_cast<const float4*>(wb + 8);
      float4 w3 = *reinterpret_cast<const float4*>(wb + 12);
      *reinterpret_cast<float4*>(&Ws[wk][wc + 0])  = w0;
      *reinterpret_cast<float4*>(&Ws[wk][wc + 4])  = w1;
      *reinterpret_cast<float4*>(&Ws[wk][wc + 8])  = w2;
      *reinterpret_cast<float4*>(&Ws[wk][wc + 12]) = w3;
    }
    __syncthreads();

#pragma unroll
    for (int k = 0; k < BK; k++) {
      const float4 a4 = *reinterpret_cast<const float4*>(&As[k][tm * 4]);
      const float4 b0 = *reinterpret_cast<const float4*>(&Ws[k][tn * 8]);
      const float4 b1 = *reinterpret_cast<const float4*>(&Ws[k][tn * 8 + 4]);
      const float a[4] = {a4.x, a4.y, a4.z, a4.w};
      const float b[8] = {b0.x, b0.y, b0.z, b0.w, b1.x, b1.y, b1.z, b1.w};
#pragma unroll
      for (int i = 0; i < 4; i++)
#pragma unroll
        for (int j = 0; j < 8; j++) acc[i][j] = fmaf(a[i], b[j], acc[i][j]);
    }
  }

  const float4 bb0 = *reinterpret_cast<const float4*>(&bias[tn * 8]);
  const float4 bb1 = *reinterpret_cast<const float4*>(&bias[tn * 8 + 4]);
  const float bb[8] = {bb0.x, bb0.y, bb0.z, bb0.w, bb1.x, bb1.y, bb1.z, bb1.w};
#pragma unroll
  for (int i = 0; i < 4; i++) {
    const int row = blockIdx.x * BM + tm * 4 + i;
    if (row < nrows) {
      float o[8];
#pragma unroll
      for (int j = 0; j < 8; j++) {
        float v = acc[i][j] + bb[j];
        o[j] = RELU ? fmaxf(v, 0.0f) : v;
      }
      float4* dst = reinterpret_cast<float4*>(out + (size_t)row * HD + tn * 8);
      dst[0] = make_float4(o[0], o[1], o[2], o[3]);
      dst[1] = make_float4(o[4], o[5], o[6], o[7]);
    }
  }
}

extern "C" void kernel_launch(void* const* d_in, const int* in_sizes, int n_in,
                              void* d_out, int out_size, void* d_ws, size_t ws_size,
                              hipStream_t stream) {
  const float* x    = (const float*)d_in[0];
  const int*   pos  = (const int*)d_in[1];
  const int*   neg  = (const int*)d_in[2];
  const float* W_in = (const float*)d_in[3];
  const float* b_in = (const float*)d_in[4];
  const float* W1pl = (const float*)d_in[5];
  const float* W1pr = (const float*)d_in[6];
  const float* b1p  = (const float*)d_in[7];
  const float* W1nl = (const float*)d_in[8];
  const float* W1nr = (const float*)d_in[9];
  const float* b1n  = (const float*)d_in[10];
  const float* W2pl = (const float*)d_in[11];
  const float* W2pr = (const float*)d_in[12];
  const float* b2p  = (const float*)d_in[13];
  const float* W2nl = (const float*)d_in[14];
  const float* W2nr = (const float*)d_in[15];
  const float* b2n  = (const float*)d_in[16];

  const size_t FM = (size_t)NN * HD;
  float* ws   = (float*)d_ws;
  float* h    = ws;
  float* mP   = h + FM;
  float* mN   = mP + FM;
  int*   degP = (int*)(mN + FM);
  int*   degN = degP + NN;
  int*   offP = degN + NN;
  int*   offN = offP + NN;
  int*   curP = offN + NN;
  int*   curN = curP + NN;
  int*   bsP  = curN + NN;
  int*   bsN  = bsP + 256;
  int*   csrP = bsN + 256;
  int*   csrN = csrP + EE;
  float* Wb1  = (float*)(csrN + EE);
  float* Wb2  = Wb1 + 384 * HD;
  float* bi1  = Wb2 + 384 * HD;
  float* bi2  = bi1 + HD;
  float* wend = bi2 + HD;

  // z lives in ws if it fits, else aliases d_out (safe: gemm3 blocks read only
  // their own 64 z-rows before writing those same rows; rows disjoint per block)
  const size_t need_with_z = ((size_t)(wend - ws) + FM) * sizeof(float);
  float* z = (ws_size >= need_with_z) ? wend : (float*)d_out;

  hipMemsetAsync(degP, 0, 2 * NN * sizeof(int), stream);  // degP+degN contiguous

  k_deg<<<(EE + 255) / 256, 256, 0, stream>>>(pos, neg, degP, degN);

  const int nb = (NN + SB - 1) / SB;  // 98
  k_scan1<<<nb, SB, 0, stream>>>(degP, offP, bsP, NN);
  k_scan2<<<1, 256, 0, stream>>>(bsP, nb);
  k_scan3<<<nb, SB, 0, stream>>>(offP, bsP, NN);
  k_scan1<<<nb, SB, 0, stream>>>(degN, offN, bsN, NN);
  k_scan2<<<1, 256, 0, stream>>>(bsN, nb);
  k_scan3<<<nb, SB, 0, stream>>>(offN, bsN, NN);

  hipMemcpyAsync(curP, offP, NN * sizeof(int), hipMemcpyDeviceToDevice, stream);
  hipMemcpyAsync(curN, offN, NN * sizeof(int), hipMemcpyDeviceToDevice, stream);
  k_fill<<<(EE + 255) / 256, 256, 0, stream>>>(pos, curP, csrP);
  k_fill<<<(EE + 255) / 256, 256, 0, stream>>>(neg, curN, csrN);

  k_build_w1<<<192, 256, 0, stream>>>(W1pl, W1pr, W1nl, W1nr, b1p, b1n, Wb1, bi1);
  k_build_w2<<<192, 256, 0, stream>>>(W2pl, W2pr, W2nl, W2nr, b2p, b2n, Wb2, bi2);

  const int gemm_grid = (NN + 63) / 64;
  k_gemm<CIN, CIN, false><<<gemm_grid, 256, 0, stream>>>(
      x, nullptr, nullptr, W_in, b_in, h, NN);

  const int gather_grid = (NN + 3) / 4;
  k_gather<<<gather_grid, 256, 0, stream>>>(h, offP, degP, csrP, mP);
  k_gather<<<gather_grid, 256, 0, stream>>>(h, offN, degN, csrN, mN);

  k_gemm<384, HD, true><<<gemm_grid, 256, 0, stream>>>(
      mP, h, mN, Wb1, bi1, z, NN);

  k_gather<<<gather_grid, 256, 0, stream>>>(z, offP, degP, csrP, mP);
  k_gather<<<gather_grid, 256, 0, stream>>>(z, offN, degN, csrN, mN);

  k_gemm<384, HD, true><<<gemm_grid, 256, 0, stream>>>(
      mP, mN, z, Wb2, bi2, (float*)d_out, NN);
}

// Round 3
// 542.800 us; speedup vs baseline: 97.9582x; 1.7124x over previous
//
#include <hip/hip_runtime.h>
#include <cstddef>
#include <cstdint>

#define NN  100000
#define EE  1000000
#define CIN 256
#define HD  128
#define HF  64
#define SB  1024

typedef __bf16 bfx8 __attribute__((ext_vector_type(8)));
typedef float f32x4 __attribute__((ext_vector_type(4)));

static __device__ __forceinline__ ushort f2b(float f) {
  union { float f; uint u; } v; v.f = f;
  uint r = v.u + 0x7fffu + ((v.u >> 16) & 1u);
  return (ushort)(r >> 16);
}
static __device__ __forceinline__ float b2f_lo(uint u) {
  union { uint u; float f; } v; v.u = u << 16; return v.f;
}
static __device__ __forceinline__ float b2f_hi(uint u) {
  union { uint u; float f; } v; v.u = u & 0xffff0000u; return v.f;
}

// ---------------- degree count ----------------
__global__ __launch_bounds__(256) void k_deg(const int* __restrict__ pos,
                                             const int* __restrict__ neg,
                                             int* __restrict__ dp,
                                             int* __restrict__ dn) {
  int i = blockIdx.x * 256 + threadIdx.x;
  if (i < EE) {
    atomicAdd(&dp[pos[EE + i]], 1);
    atomicAdd(&dn[neg[EE + i]], 1);
  }
}

// ---------------- exclusive scan (3 kernels) ----------------
__global__ __launch_bounds__(SB) void k_scan1(const int* __restrict__ deg,
                                              int* __restrict__ off,
                                              int* __restrict__ bsum, int n) {
  __shared__ int s[SB];
  int i = blockIdx.x * SB + threadIdx.x;
  int v = (i < n) ? deg[i] : 0;
  s[threadIdx.x] = v;
  __syncthreads();
  for (int d = 1; d < SB; d <<= 1) {
    int t = (threadIdx.x >= d) ? s[threadIdx.x - d] : 0;
    __syncthreads();
    s[threadIdx.x] += t;
    __syncthreads();
  }
  if (i < n) off[i] = s[threadIdx.x] - v;  // exclusive
  if (threadIdx.x == SB - 1) bsum[blockIdx.x] = s[SB - 1];
}

__global__ __launch_bounds__(256) void k_scan2(int* __restrict__ bsum, int nb) {
  __shared__ int s[256];
  int v = (threadIdx.x < nb) ? bsum[threadIdx.x] : 0;
  s[threadIdx.x] = v;
  __syncthreads();
  for (int d = 1; d < 256; d <<= 1) {
    int t = (threadIdx.x >= d) ? s[threadIdx.x - d] : 0;
    __syncthreads();
    s[threadIdx.x] += t;
    __syncthreads();
  }
  if (threadIdx.x < nb) bsum[threadIdx.x] = s[threadIdx.x] - v;  // exclusive
}

__global__ __launch_bounds__(SB) void k_scan3(int* __restrict__ off,
                                              const int* __restrict__ bsum, int n) {
  int i = blockIdx.x * SB + threadIdx.x;
  if (i < n) off[i] += bsum[blockIdx.x];
}

// ---------------- CSR fill ----------------
__global__ __launch_bounds__(256) void k_fill(const int* __restrict__ ei,
                                              int* __restrict__ cur,
                                              int* __restrict__ csr) {
  int e = blockIdx.x * 256 + threadIdx.x;
  if (e < EE) {
    int dst = ei[EE + e];
    int p = atomicAdd(&cur[dst], 1);
    csr[p] = ei[e];
  }
}

// ---------------- gather mean-aggregate (bf16 feat): one wave per node ----------------
__global__ __launch_bounds__(256) void k_gather(const ushort* __restrict__ feat,
                                                const int* __restrict__ off,
                                                const int* __restrict__ deg,
                                                const int* __restrict__ csr,
                                                ushort* __restrict__ out) {
  int wid = threadIdx.x >> 6, lane = threadIdx.x & 63;
  int node = blockIdx.x * 4 + wid;
  if (node >= NN) return;
  int start = off[node], d = deg[node];
  const uint* f = (const uint*)feat;  // 64 uints per 128-bf16 row
  float ax = 0.f, ay = 0.f;
  int k = 0;
  for (; k + 4 <= d; k += 4) {
    int s0 = csr[start + k], s1 = csr[start + k + 1];
    int s2 = csr[start + k + 2], s3 = csr[start + k + 3];
    uint u0 = f[(size_t)s0 * 64 + lane];
    uint u1 = f[(size_t)s1 * 64 + lane];
    uint u2 = f[(size_t)s2 * 64 + lane];
    uint u3 = f[(size_t)s3 * 64 + lane];
    ax += (b2f_lo(u0) + b2f_lo(u1)) + (b2f_lo(u2) + b2f_lo(u3));
    ay += (b2f_hi(u0) + b2f_hi(u1)) + (b2f_hi(u2) + b2f_hi(u3));
  }
  for (; k < d; k++) {
    uint u = f[(size_t)csr[start + k] * 64 + lane];
    ax += b2f_lo(u);
    ay += b2f_hi(u);
  }
  float sc = 1.0f / fmaxf((float)d, 1.0f);
  ((uint*)out)[(size_t)node * 64 + lane] =
      (uint)f2b(ax * sc) | ((uint)f2b(ay * sc) << 16);
}

// ---------------- weight builders: f32 -> bf16, transposed to n-major ----------------
__global__ __launch_bounds__(256) void k_build_w0(const float* __restrict__ Wi,
                                                  ushort* __restrict__ Wb) {
  int idx = blockIdx.x * 256 + threadIdx.x;  // over CIN*HD
  if (idx >= CIN * HD) return;
  int k = idx >> 7, j = idx & 127;
  Wb[j * CIN + k] = f2b(Wi[idx]);
}

// Layer1 mapping (validated rounds 0-2): A = [aggP(128) | h(128) | aggN(128)]
__global__ __launch_bounds__(256) void k_build_w1(const float* __restrict__ Wpl, const float* __restrict__ Wpr,
                                                  const float* __restrict__ Wnl, const float* __restrict__ Wnr,
                                                  const float* __restrict__ bp, const float* __restrict__ bn,
                                                  ushort* __restrict__ Wbig, float* __restrict__ bias) {
  int idx = blockIdx.x * 256 + threadIdx.x;
  if (idx < HD) bias[idx] = (idx < HF) ? bp[idx] : bn[idx - HF];
  if (idx >= 384 * HD) return;
  int k = idx >> 7, j = idx & 127;
  float v = 0.0f;
  if (k < 128)      { if (j <  HF) v = Wpl[k * HF + j]; }
  else if (k < 256) { v = (j < HF) ? Wpr[(k - 128) * HF + j] : Wnr[(k - 128) * HF + (j - HF)]; }
  else              { if (j >= HF) v = Wnl[(k - 256) * HF + (j - HF)]; }
  Wbig[j * 384 + k] = f2b(v);  // n-major
}

// Layer2 mapping (validated rounds 0-2): A = [meanP(z) | meanN(z) | z]
__global__ __launch_bounds__(256) void k_build_w2(const float* __restrict__ Wpl, const float* __restrict__ Wpr,
                                                  const float* __restrict__ Wnl, const float* __restrict__ Wnr,
                                                  const float* __restrict__ bp, const float* __restrict__ bn,
                                                  ushort* __restrict__ Wbig, float* __restrict__ bias) {
  int idx = blockIdx.x * 256 + threadIdx.x;
  if (idx < HD) bias[idx] = (idx < HF) ? bp[idx] : bn[idx - HF];
  if (idx >= 384 * HD) return;
  int k = idx >> 7, j = idx & 127;
  float v = 0.0f;
  if (k < 64)       { if (j <  HF) v = Wpl[k * HF + j]; }
  else if (k < 128) { if (j >= HF) v = Wnl[(k - 64) * HF + (j - HF)]; }
  else if (k < 192) { if (j >= HF) v = Wnl[(k - 128 + 64) * HF + (j - HF)]; }
  else if (k < 256) { if (j <  HF) v = Wpl[(k - 192 + 64) * HF + j]; }
  else if (k < 320) { if (j <  HF) v = Wpr[(k - 256) * HF + j]; }
  else              { if (j >= HF) v = Wnr[(k - 320) * HF + (j - HF)]; }
  Wbig[j * 384 + k] = f2b(v);  // n-major
}

// ---------------- MFMA GEMM: out = relu?(gather(A)@W + bias) ----------------
// BM=128 rows/block, BK=32, Nout=128. 256 threads = 4 waves, each wave a 64x64
// quadrant = 4x4 frags of 16x16x32 bf16 MFMA. LDS rows padded to 40 bf16
// (80B stride -> 2-way bank aliasing max, free per m136).
// W is n-major bf16 [HD][KTOT]. A: either one f32 source (width KTOT) or
// three bf16 sources of width 128 each (k-chunk c selects source c*32/128).
template <int KTOT, bool F32SRC, bool RELU, bool OUTF32>
__global__ __launch_bounds__(256) void k_mfma(const void* A0v, const void* A1v, const void* A2v,
                                              const ushort* __restrict__ W,
                                              const float* __restrict__ bias,
                                              void* outv, int nrows) {
  constexpr int BM = 128, BK = 32, NCH = KTOT / BK, LSTR = 40;
  __shared__ ushort As[BM * LSTR];
  __shared__ ushort Bs[HD * LSTR];

  const int tid = threadIdx.x;
  const int bm = blockIdx.x * BM;

  const int srow = tid >> 1;   // staging row 0..127 (A row / W n-row)
  const int sseg = tid & 1;    // 16-bf16 segment within the 32-wide chunk
  const int grow = bm + srow;
  const bool rok = grow < nrows;

  const int wv = tid >> 6, lane = tid & 63;
  const int wr = (wv >> 1) * 64, wc = (wv & 1) * 64;
  const int lrow = lane & 15, kg = (lane >> 4) * 8;

  f32x4 acc[4][4] = {};

#pragma unroll 1
  for (int c = 0; c < NCH; c++) {
    const int col0 = c * BK;
    __syncthreads();
    // ---- stage A chunk (128 rows x 32 k)
    if constexpr (F32SRC) {
      ushort tmp[16];
      if (rok) {
        const float* p = (const float*)A0v + (size_t)grow * KTOT + col0 + sseg * 16;
#pragma unroll
        for (int j = 0; j < 16; j++) tmp[j] = f2b(p[j]);
      } else {
#pragma unroll
        for (int j = 0; j < 16; j++) tmp[j] = 0;
      }
      *reinterpret_cast<uint4*>(&As[srow * LSTR + sseg * 16]) =
          *reinterpret_cast<uint4*>(&tmp[0]);
      *reinterpret_cast<uint4*>(&As[srow * LSTR + sseg * 16 + 8]) =
          *reinterpret_cast<uint4*>(&tmp[8]);
    } else {
      const int s = col0 >> 7, lc = col0 & 127;
      const ushort* Ap = (const ushort*)((s == 0) ? A0v : (s == 1) ? A1v : A2v);
      uint4 u0 = make_uint4(0, 0, 0, 0), u1 = u0;
      if (rok) {
        const ushort* p = Ap + (size_t)grow * HD + lc + sseg * 16;
        u0 = *reinterpret_cast<const uint4*>(p);
        u1 = *reinterpret_cast<const uint4*>(p + 8);
      }
      *reinterpret_cast<uint4*>(&As[srow * LSTR + sseg * 16]) = u0;
      *reinterpret_cast<uint4*>(&As[srow * LSTR + sseg * 16 + 8]) = u1;
    }
    // ---- stage B chunk (128 n x 32 k) from n-major W
    {
      const ushort* p = W + (size_t)srow * KTOT + col0 + sseg * 16;
      uint4 u0 = *reinterpret_cast<const uint4*>(p);
      uint4 u1 = *reinterpret_cast<const uint4*>(p + 8);
      *reinterpret_cast<uint4*>(&Bs[srow * LSTR + sseg * 16]) = u0;
      *reinterpret_cast<uint4*>(&Bs[srow * LSTR + sseg * 16 + 8]) = u1;
    }
    __syncthreads();

    bfx8 a[4], b[4];
#pragma unroll
    for (int m = 0; m < 4; m++)
      a[m] = *reinterpret_cast<const bfx8*>(&As[(wr + m * 16 + lrow) * LSTR + kg]);
#pragma unroll
    for (int n = 0; n < 4; n++)
      b[n] = *reinterpret_cast<const bfx8*>(&Bs[(wc + n * 16 + lrow) * LSTR + kg]);
#pragma unroll
    for (int m = 0; m < 4; m++)
#pragma unroll
      for (int n = 0; n < 4; n++)
        acc[m][n] = __builtin_amdgcn_mfma_f32_16x16x32_bf16(a[m], b[n], acc[m][n], 0, 0, 0);
  }

  // ---- epilogue: C frag layout col=lane&15, row=(lane>>4)*4+reg (m89/m91)
  const int r4 = (lane >> 4) * 4;
  float bcol[4];
#pragma unroll
  for (int n = 0; n < 4; n++) bcol[n] = bias[wc + n * 16 + lrow];
#pragma unroll
  for (int m = 0; m < 4; m++) {
#pragma unroll
    for (int i = 0; i < 4; i++) {
      const int row = bm + wr + m * 16 + r4 + i;
      if (row < nrows) {
#pragma unroll
        for (int n = 0; n < 4; n++) {
          float v = acc[m][n][i] + bcol[n];
          if (RELU) v = fmaxf(v, 0.0f);
          const int col = wc + n * 16 + lrow;
          if (OUTF32) ((float*)outv)[(size_t)row * HD + col] = v;
          else        ((ushort*)outv)[(size_t)row * HD + col] = f2b(v);
        }
      }
    }
  }
}

extern "C" void kernel_launch(void* const* d_in, const int* in_sizes, int n_in,
                              void* d_out, int out_size, void* d_ws, size_t ws_size,
                              hipStream_t stream) {
  const float* x    = (const float*)d_in[0];
  const int*   pos  = (const int*)d_in[1];
  const int*   neg  = (const int*)d_in[2];
  const float* W_in = (const float*)d_in[3];
  const float* b_in = (const float*)d_in[4];
  const float* W1pl = (const float*)d_in[5];
  const float* W1pr = (const float*)d_in[6];
  const float* b1p  = (const float*)d_in[7];
  const float* W1nl = (const float*)d_in[8];
  const float* W1nr = (const float*)d_in[9];
  const float* b1n  = (const float*)d_in[10];
  const float* W2pl = (const float*)d_in[11];
  const float* W2pr = (const float*)d_in[12];
  const float* b2p  = (const float*)d_in[13];
  const float* W2nl = (const float*)d_in[14];
  const float* W2nr = (const float*)d_in[15];
  const float* b2n  = (const float*)d_in[16];

  const size_t FM = (size_t)NN * HD;  // elements per feature matrix
  ushort* h   = (ushort*)d_ws;
  ushort* mP  = h + FM;
  ushort* mN  = mP + FM;
  ushort* z   = mN + FM;
  int* degP = (int*)(z + FM);
  int* degN = degP + NN;
  int* offP = degN + NN;
  int* offN = offP + NN;
  int* curP = offN + NN;
  int* curN = curP + NN;
  int* bsP  = curN + NN;
  int* bsN  = bsP + 256;
  int* csrP = bsN + 256;
  int* csrN = csrP + EE;
  ushort* Wb0 = (ushort*)(csrN + EE);
  ushort* Wb1 = Wb0 + CIN * HD;
  ushort* Wb2 = Wb1 + 384 * HD;
  float*  bi1 = (float*)(Wb2 + 384 * HD);
  float*  bi2 = bi1 + HD;

  hipMemsetAsync(degP, 0, 2 * NN * sizeof(int), stream);

  k_deg<<<(EE + 255) / 256, 256, 0, stream>>>(pos, neg, degP, degN);

  const int nb = (NN + SB - 1) / SB;  // 98
  k_scan1<<<nb, SB, 0, stream>>>(degP, offP, bsP, NN);
  k_scan2<<<1, 256, 0, stream>>>(bsP, nb);
  k_scan3<<<nb, SB, 0, stream>>>(offP, bsP, NN);
  k_scan1<<<nb, SB, 0, stream>>>(degN, offN, bsN, NN);
  k_scan2<<<1, 256, 0, stream>>>(bsN, nb);
  k_scan3<<<nb, SB, 0, stream>>>(offN, bsN, NN);

  hipMemcpyAsync(curP, offP, NN * sizeof(int), hipMemcpyDeviceToDevice, stream);
  hipMemcpyAsync(curN, offN, NN * sizeof(int), hipMemcpyDeviceToDevice, stream);
  k_fill<<<(EE + 255) / 256, 256, 0, stream>>>(pos, curP, csrP);
  k_fill<<<(EE + 255) / 256, 256, 0, stream>>>(neg, curN, csrN);

  k_build_w0<<<(CIN * HD + 255) / 256, 256, 0, stream>>>(W_in, Wb0);
  k_build_w1<<<192, 256, 0, stream>>>(W1pl, W1pr, W1nl, W1nr, b1p, b1n, Wb1, bi1);
  k_build_w2<<<192, 256, 0, stream>>>(W2pl, W2pr, W2nl, W2nr, b2p, b2n, Wb2, bi2);

  const int gemm_grid = (NN + 127) / 128;  // 782
  // layer 0: h = x @ W_in + b_in   (f32 src, bf16 out, no relu)
  k_mfma<CIN, true, false, false><<<gemm_grid, 256, 0, stream>>>(
      x, nullptr, nullptr, Wb0, b_in, h, NN);

  const int gather_grid = (NN + 3) / 4;
  k_gather<<<gather_grid, 256, 0, stream>>>(h, offP, degP, csrP, mP);
  k_gather<<<gather_grid, 256, 0, stream>>>(h, offN, degN, csrN, mN);

  // layer 1: z = relu([mP | h | mN] @ Wb1 + bi1)   (bf16 out)
  k_mfma<384, false, true, false><<<gemm_grid, 256, 0, stream>>>(
      mP, h, mN, Wb1, bi1, z, NN);

  k_gather<<<gather_grid, 256, 0, stream>>>(z, offP, degP, csrP, mP);
  k_gather<<<gather_grid, 256, 0, stream>>>(z, offN, degN, csrN, mN);

  // layer 2: out = relu([mP | mN | z] @ Wb2 + bi2)  (f32 out to d_out)
  k_mfma<384, false, true, true><<<gemm_grid, 256, 0, stream>>>(
      mP, mN, z, Wb2, bi2, (float*)d_out, NN);
}

// Round 4
// 533.904 us; speedup vs baseline: 99.5905x; 1.0167x over previous
//
#include <hip/hip_runtime.h>
#include <cstddef>
#include <cstdint>

#define NN  100000
#define EE  1000000
#define CIN 256
#define HD  128
#define HF  64
#define SB  1024

typedef __bf16 bfx8 __attribute__((ext_vector_type(8)));
typedef float f32x4 __attribute__((ext_vector_type(4)));

static __device__ __forceinline__ ushort f2b(float f) {
  union { float f; uint u; } v; v.f = f;
  uint r = v.u + 0x7fffu + ((v.u >> 16) & 1u);
  return (ushort)(r >> 16);
}
static __device__ __forceinline__ float b2f(ushort u) {
  union { uint u; float f; } v; v.u = (uint)u << 16; return v.f;
}
static __device__ __forceinline__ float b2f_lo(uint u) {
  union { uint u; float f; } v; v.u = u << 16; return v.f;
}
static __device__ __forceinline__ float b2f_hi(uint u) {
  union { uint u; float f; } v; v.u = u & 0xffff0000u; return v.f;
}

// ---------------- degree count: 4 edges/thread, int4 loads ----------------
__global__ __launch_bounds__(256) void k_deg(const int* __restrict__ pos,
                                             const int* __restrict__ neg,
                                             int* __restrict__ deg) {
  int base = (blockIdx.x * 256 + threadIdx.x) * 4;
  if (base >= EE) return;
  int4 dp = *reinterpret_cast<const int4*>(pos + EE + base);
  int4 dn = *reinterpret_cast<const int4*>(neg + EE + base);
  atomicAdd(&deg[dp.x], 1); atomicAdd(&deg[dp.y], 1);
  atomicAdd(&deg[dp.z], 1); atomicAdd(&deg[dp.w], 1);
  atomicAdd(&deg[NN + dn.x], 1); atomicAdd(&deg[NN + dn.y], 1);
  atomicAdd(&deg[NN + dn.z], 1); atomicAdd(&deg[NN + dn.w], 1);
}

// ---------------- exclusive scan (grid.y = {pos,neg}) ----------------
__global__ __launch_bounds__(SB) void k_scan1(const int* __restrict__ deg,
                                              int* __restrict__ off,
                                              int* __restrict__ bsum) {
  int y = blockIdx.y;
  const int* d = deg + (size_t)y * NN;
  int* o = off + (size_t)y * NN;
  __shared__ int s[SB];
  int i = blockIdx.x * SB + threadIdx.x;
  int v = (i < NN) ? d[i] : 0;
  s[threadIdx.x] = v;
  __syncthreads();
  for (int dd = 1; dd < SB; dd <<= 1) {
    int t = (threadIdx.x >= dd) ? s[threadIdx.x - dd] : 0;
    __syncthreads();
    s[threadIdx.x] += t;
    __syncthreads();
  }
  if (i < NN) o[i] = s[threadIdx.x] - v;  // exclusive
  if (threadIdx.x == SB - 1) bsum[y * 128 + blockIdx.x] = s[SB - 1];
}

__global__ __launch_bounds__(256) void k_scan2(int* __restrict__ bsum, int nb) {
  int* bs = bsum + blockIdx.x * 128;
  __shared__ int s[256];
  int v = (threadIdx.x < nb) ? bs[threadIdx.x] : 0;
  s[threadIdx.x] = v;
  __syncthreads();
  for (int dd = 1; dd < 256; dd <<= 1) {
    int t = (threadIdx.x >= dd) ? s[threadIdx.x - dd] : 0;
    __syncthreads();
    s[threadIdx.x] += t;
    __syncthreads();
  }
  if (threadIdx.x < nb) bs[threadIdx.x] = s[threadIdx.x] - v;  // exclusive
}

__global__ __launch_bounds__(SB) void k_scan3(int* __restrict__ off,
                                              const int* __restrict__ bsum,
                                              int* __restrict__ cur) {
  int y = blockIdx.y;
  int i = blockIdx.x * SB + threadIdx.x;
  if (i < NN) {
    int v = off[(size_t)y * NN + i] + bsum[y * 128 + blockIdx.x];
    off[(size_t)y * NN + i] = v;
    cur[(size_t)y * NN + i] = v;
  }
}

// ---------------- CSR fill (both lists fused) ----------------
__global__ __launch_bounds__(256) void k_fill(const int* __restrict__ pos,
                                              const int* __restrict__ neg,
                                              int* __restrict__ cur,
                                              int* __restrict__ csrP,
                                              int* __restrict__ csrN) {
  int e = blockIdx.x * 256 + threadIdx.x;
  if (e >= EE) return;
  int sp = pos[e], dp = pos[EE + e];
  int sn = neg[e], dn = neg[EE + e];
  int p = atomicAdd(&cur[dp], 1);
  csrP[p] = sp;
  int q = atomicAdd(&cur[NN + dn], 1);
  csrN[q] = sn;
}

// ---------------- builder: Wc = W_in @ [W1pl|W1nl|W1pr|W1nr], n-major bf16 ----------------
// bc = b_in @ [same] + [0|0|b1p|b1n]
__global__ __launch_bounds__(256) void k_bw1(const float* __restrict__ W_in,
                                             const float* __restrict__ W1pl, const float* __restrict__ W1pr,
                                             const float* __restrict__ W1nl, const float* __restrict__ W1nr,
                                             const float* __restrict__ b_in,
                                             const float* __restrict__ b1p, const float* __restrict__ b1n,
                                             ushort* __restrict__ Wcb, float* __restrict__ bc) {
  int k = blockIdx.x;   // 0..255: x-dim
  int j = threadIdx.x;  // 0..255: output col [PA1|NA1|R1p|R1n]
  const float* src; int jj;
  if (j < 64)       { src = W1pl; jj = j; }
  else if (j < 128) { src = W1nl; jj = j - 64; }
  else if (j < 192) { src = W1pr; jj = j - 128; }
  else              { src = W1nr; jj = j - 192; }
  float acc = 0.f;
  for (int m = 0; m < HD; m++) acc = fmaf(W_in[k * HD + m], src[m * HF + jj], acc);
  Wcb[j * CIN + k] = f2b(acc);  // n-major
  if (k == 0) {
    float b = 0.f;
    for (int m = 0; m < HD; m++) b = fmaf(b_in[m], src[m * HF + jj], b);
    if (j >= 128) b += (j < 192) ? b1p[j - 128] : b1n[j - 192];
    bc[j] = b;
  }
}

// ---------------- builder: W2c (128x384) mapping, n-major bf16 ----------------
// cols 0-127: PA2 (meanP target), 128-255: NA2 (meanN), 256-383: R2 (direct)
__global__ __launch_bounds__(256) void k_bw2(const float* __restrict__ W2pl, const float* __restrict__ W2pr,
                                             const float* __restrict__ W2nl, const float* __restrict__ W2nr,
                                             const float* __restrict__ b2p, const float* __restrict__ b2n,
                                             ushort* __restrict__ W2cb, float* __restrict__ b2c) {
  int idx = blockIdx.x * 256 + threadIdx.x;
  if (idx < 384) {
    float b = 0.f;
    if (idx >= 256) b = (idx < 320) ? b2p[idx - 256] : b2n[idx - 320];
    b2c[idx] = b;
  }
  if (idx >= 384 * HD) return;
  int j = idx / HD, k = idx % HD;  // j: output col, k: z-dim
  float v = 0.f;
  if (j < 64)       { if (k < 64)  v = W2pl[k * HF + j]; }                  // zp@W2pl_top -> out_p
  else if (j < 128) { if (k >= 64) v = W2nl[(k - 64) * HF + (j - 64)]; }    // zn@W2nl_top -> out_n
  else if (j < 192) { if (k >= 64) v = W2pl[k * HF + (j - 128)]; }          // zn@W2pl_bot -> out_p
  else if (j < 256) { if (k < 64)  v = W2nl[(k + 64) * HF + (j - 192)]; }   // zp@W2nl_bot -> out_n
  else if (j < 320) { if (k < 64)  v = W2pr[k * HF + (j - 256)]; }          // zp@W2pr -> out_p
  else              { if (k >= 64) v = W2nr[(k - 64) * HF + (j - 320)]; }   // zn@W2nr -> out_n
  W2cb[j * HD + k] = f2b(v);  // n-major
}

// ---------------- MFMA GEMM: out(bf16) = A @ W + bias (no relu) ----------------
// BM=128 rows/block, BK=32. grid.y = 128-col panel. 4 waves, each a 64x64
// quadrant (4x4 frags of 16x16x32 bf16). LDS rows padded to 40 bf16 (2-way max).
// Frag/C-layout validated round 3 (absmax 0.031).
template <int KTOT, int PANELS, bool F32SRC>
__global__ __launch_bounds__(256) void k_mfma(const void* __restrict__ Av,
                                              const ushort* __restrict__ W,
                                              const float* __restrict__ bias,
                                              ushort* __restrict__ out, int nrows) {
  constexpr int BM = 128, BK = 32, NCH = KTOT / BK, LSTR = 40, OUTW = PANELS * HD;
  __shared__ ushort As[BM * LSTR];
  __shared__ ushort Bs[HD * LSTR];

  const int tid = threadIdx.x;
  const int bm = blockIdx.x * BM;
  const int py = blockIdx.y;

  const int srow = tid >> 1;
  const int sseg = tid & 1;
  const int grow = bm + srow;
  const bool rok = grow < nrows;

  const int wv = tid >> 6, lane = tid & 63;
  const int wr = (wv >> 1) * 64, wc = (wv & 1) * 64;
  const int lrow = lane & 15, kg = (lane >> 4) * 8;

  const ushort* Wp = W + (size_t)(py * HD) * KTOT;

  f32x4 acc[4][4] = {};

#pragma unroll 1
  for (int c = 0; c < NCH; c++) {
    const int col0 = c * BK;
    __syncthreads();
    if constexpr (F32SRC) {
      ushort tmp[16];
      if (rok) {
        const float4* p = reinterpret_cast<const float4*>(
            (const float*)Av + (size_t)grow * KTOT + col0 + sseg * 16);
        float4 f0 = p[0], f1 = p[1], f2_ = p[2], f3 = p[3];
        tmp[0] = f2b(f0.x);  tmp[1] = f2b(f0.y);  tmp[2] = f2b(f0.z);  tmp[3] = f2b(f0.w);
        tmp[4] = f2b(f1.x);  tmp[5] = f2b(f1.y);  tmp[6] = f2b(f1.z);  tmp[7] = f2b(f1.w);
        tmp[8] = f2b(f2_.x); tmp[9] = f2b(f2_.y); tmp[10] = f2b(f2_.z); tmp[11] = f2b(f2_.w);
        tmp[12] = f2b(f3.x); tmp[13] = f2b(f3.y); tmp[14] = f2b(f3.z); tmp[15] = f2b(f3.w);
      } else {
#pragma unroll
        for (int j = 0; j < 16; j++) tmp[j] = 0;
      }
      *reinterpret_cast<uint4*>(&As[srow * LSTR + sseg * 16]) = *reinterpret_cast<uint4*>(&tmp[0]);
      *reinterpret_cast<uint4*>(&As[srow * LSTR + sseg * 16 + 8]) = *reinterpret_cast<uint4*>(&tmp[8]);
    } else {
      uint4 u0 = make_uint4(0, 0, 0, 0), u1 = u0;
      if (rok) {
        const ushort* p = (const ushort*)Av + (size_t)grow * KTOT + col0 + sseg * 16;
        u0 = *reinterpret_cast<const uint4*>(p);
        u1 = *reinterpret_cast<const uint4*>(p + 8);
      }
      *reinterpret_cast<uint4*>(&As[srow * LSTR + sseg * 16]) = u0;
      *reinterpret_cast<uint4*>(&As[srow * LSTR + sseg * 16 + 8]) = u1;
    }
    {
      const ushort* p = Wp + (size_t)srow * KTOT + col0 + sseg * 16;
      uint4 u0 = *reinterpret_cast<const uint4*>(p);
      uint4 u1 = *reinterpret_cast<const uint4*>(p + 8);
      *reinterpret_cast<uint4*>(&Bs[srow * LSTR + sseg * 16]) = u0;
      *reinterpret_cast<uint4*>(&Bs[srow * LSTR + sseg * 16 + 8]) = u1;
    }
    __syncthreads();

    bfx8 a[4], b[4];
#pragma unroll
    for (int m = 0; m < 4; m++)
      a[m] = *reinterpret_cast<const bfx8*>(&As[(wr + m * 16 + lrow) * LSTR + kg]);
#pragma unroll
    for (int n = 0; n < 4; n++)
      b[n] = *reinterpret_cast<const bfx8*>(&Bs[(wc + n * 16 + lrow) * LSTR + kg]);
#pragma unroll
    for (int m = 0; m < 4; m++)
#pragma unroll
      for (int n = 0; n < 4; n++)
        acc[m][n] = __builtin_amdgcn_mfma_f32_16x16x32_bf16(a[m], b[n], acc[m][n], 0, 0, 0);
  }

  const int r4 = (lane >> 4) * 4;
  float bcol[4];
#pragma unroll
  for (int n = 0; n < 4; n++) bcol[n] = bias[py * HD + wc + n * 16 + lrow];
#pragma unroll
  for (int m = 0; m < 4; m++) {
#pragma unroll
    for (int i = 0; i < 4; i++) {
      const int row = bm + wr + m * 16 + r4 + i;
      if (row < nrows) {
#pragma unroll
        for (int n = 0; n < 4; n++) {
          const int col = py * HD + wc + n * 16 + lrow;
          out[(size_t)row * OUTW + col] = f2b(acc[m][n][i] + bcol[n]);
        }
      }
    }
  }
}

// ---------------- gather1: z-half = relu(mean(G1 panel) + G1 R-col) ----------------
// c0 = 0 (pos -> zp) or 64 (neg -> zn). One wave/node, lane = col, ushort loads.
__global__ __launch_bounds__(256) void k_gather1(const ushort* __restrict__ G1,
                                                 const int* __restrict__ off,
                                                 const int* __restrict__ deg,
                                                 const int* __restrict__ csr,
                                                 ushort* __restrict__ z, int c0) {
  int wid = threadIdx.x >> 6, lane = threadIdx.x & 63;
  int node = blockIdx.x * 4 + wid;
  if (node >= NN) return;
  int start = off[node], d = deg[node];
  const ushort* g = G1 + c0 + lane;
  float acc = 0.f;
  int k = 0;
  for (; k + 4 <= d; k += 4) {
    int s0 = csr[start + k], s1 = csr[start + k + 1];
    int s2 = csr[start + k + 2], s3 = csr[start + k + 3];
    float a0 = b2f(g[(size_t)s0 * 256]);
    float a1 = b2f(g[(size_t)s1 * 256]);
    float a2 = b2f(g[(size_t)s2 * 256]);
    float a3 = b2f(g[(size_t)s3 * 256]);
    acc += (a0 + a1) + (a2 + a3);
  }
  for (; k < d; k++) acc += b2f(g[(size_t)csr[start + k] * 256]);
  float inv = 1.f / fmaxf((float)d, 1.f);
  float r = b2f(G1[(size_t)node * 256 + c0 + 128 + lane]);
  float v = fmaxf(acc * inv + r, 0.f);
  z[(size_t)node * HD + c0 + lane] = f2b(v);
}

// ---------------- gather2P: tmpP = meanP(G2[:,0:128]) (f32) ----------------
__global__ __launch_bounds__(256) void k_g2p(const ushort* __restrict__ G2,
                                             const int* __restrict__ off,
                                             const int* __restrict__ deg,
                                             const int* __restrict__ csr,
                                             float* __restrict__ tmpP) {
  int wid = threadIdx.x >> 6, lane = threadIdx.x & 63;
  int node = blockIdx.x * 4 + wid;
  if (node >= NN) return;
  int start = off[node], d = deg[node];
  const uint* g = (const uint*)G2;  // row stride 192 uints
  float ax = 0.f, ay = 0.f;
  int k = 0;
  for (; k + 4 <= d; k += 4) {
    int s0 = csr[start + k], s1 = csr[start + k + 1];
    int s2 = csr[start + k + 2], s3 = csr[start + k + 3];
    uint u0 = g[(size_t)s0 * 192 + lane];
    uint u1 = g[(size_t)s1 * 192 + lane];
    uint u2 = g[(size_t)s2 * 192 + lane];
    uint u3 = g[(size_t)s3 * 192 + lane];
    ax += (b2f_lo(u0) + b2f_lo(u1)) + (b2f_lo(u2) + b2f_lo(u3));
    ay += (b2f_hi(u0) + b2f_hi(u1)) + (b2f_hi(u2) + b2f_hi(u3));
  }
  for (; k < d; k++) {
    uint u = g[(size_t)csr[start + k] * 192 + lane];
    ax += b2f_lo(u); ay += b2f_hi(u);
  }
  float inv = 1.f / fmaxf((float)d, 1.f);
  reinterpret_cast<float2*>(tmpP)[(size_t)node * 64 + lane] = make_float2(ax * inv, ay * inv);
}

// ---------------- gather2N: out = relu(tmpP + meanN(G2[:,128:256]) + G2[i,256:384]) ----------------
__global__ __launch_bounds__(256) void k_g2n(const ushort* __restrict__ G2,
                                             const float* __restrict__ tmpP,
                                             const int* __restrict__ off,
                                             const int* __restrict__ deg,
                                             const int* __restrict__ csr,
                                             float* __restrict__ outp) {
  int wid = threadIdx.x >> 6, lane = threadIdx.x & 63;
  int node = blockIdx.x * 4 + wid;
  if (node >= NN) return;
  int start = off[node], d = deg[node];
  const uint* g = (const uint*)G2;
  float ax = 0.f, ay = 0.f;
  int k = 0;
  for (; k + 4 <= d; k += 4) {
    int s0 = csr[start + k], s1 = csr[start + k + 1];
    int s2 = csr[start + k + 2], s3 = csr[start + k + 3];
    uint u0 = g[(size_t)s0 * 192 + 64 + lane];
    uint u1 = g[(size_t)s1 * 192 + 64 + lane];
    uint u2 = g[(size_t)s2 * 192 + 64 + lane];
    uint u3 = g[(size_t)s3 * 192 + 64 + lane];
    ax += (b2f_lo(u0) + b2f_lo(u1)) + (b2f_lo(u2) + b2f_lo(u3));
    ay += (b2f_hi(u0) + b2f_hi(u1)) + (b2f_hi(u2) + b2f_hi(u3));
  }
  for (; k < d; k++) {
    uint u = g[(size_t)csr[start + k] * 192 + 64 + lane];
    ax += b2f_lo(u); ay += b2f_hi(u);
  }
  float inv = 1.f / fmaxf((float)d, 1.f);
  float2 t = reinterpret_cast<const float2*>(tmpP)[(size_t)node * 64 + lane];
  uint r = g[(size_t)node * 192 + 128 + lane];
  float vx = fmaxf(t.x + ax * inv + b2f_lo(r), 0.f);
  float vy = fmaxf(t.y + ay * inv + b2f_hi(r), 0.f);
  reinterpret_cast<float2*>(outp)[(size_t)node * 64 + lane] = make_float2(vx, vy);
}

extern "C" void kernel_launch(void* const* d_in, const int* in_sizes, int n_in,
                              void* d_out, int out_size, void* d_ws, size_t ws_size,
                              hipStream_t stream) {
  const float* x    = (const float*)d_in[0];
  const int*   pos  = (const int*)d_in[1];
  const int*   neg  = (const int*)d_in[2];
  const float* W_in = (const float*)d_in[3];
  const float* b_in = (const float*)d_in[4];
  const float* W1pl = (const float*)d_in[5];
  const float* W1pr = (const float*)d_in[6];
  const float* b1p  = (const float*)d_in[7];
  const float* W1nl = (const float*)d_in[8];
  const float* W1nr = (const float*)d_in[9];
  const float* b1n  = (const float*)d_in[10];
  const float* W2pl = (const float*)d_in[11];
  const float* W2pr = (const float*)d_in[12];
  const float* b2p  = (const float*)d_in[13];
  const float* W2nl = (const float*)d_in[14];
  const float* W2nr = (const float*)d_in[15];
  const float* b2n  = (const float*)d_in[16];

  ushort* G1  = (ushort*)d_ws;                       // N x 256 bf16 (51.2 MB)
  ushort* z   = G1 + (size_t)NN * 256;               // N x 128 bf16
  ushort* G2  = z + (size_t)NN * HD;                 // N x 384 bf16
  int* deg  = (int*)(G2 + (size_t)NN * 384);         // 2N
  int* off  = deg + 2 * NN;
  int* cur  = off + 2 * NN;
  int* bs   = cur + 2 * NN;                          // 256
  int* csrP = bs + 256;
  int* csrN = csrP + EE;
  ushort* Wcb  = (ushort*)(csrN + EE);               // 256 x 256
  ushort* W2cb = Wcb + 256 * 256;                    // 384 x 128
  float* bc1 = (float*)(W2cb + 384 * HD);            // 256
  float* b2c = bc1 + 256;                            // 384
  float* tmpP = (float*)G1;                          // aliases G1 (dead by then; same bytes)

  hipMemsetAsync(deg, 0, 2 * NN * sizeof(int), stream);

  k_deg<<<(EE / 4 + 255) / 256, 256, 0, stream>>>(pos, neg, deg);

  const int nb = (NN + SB - 1) / SB;  // 98
  k_scan1<<<dim3(nb, 2), SB, 0, stream>>>(deg, off, bs);
  k_scan2<<<2, 256, 0, stream>>>(bs, nb);
  k_scan3<<<dim3(nb, 2), SB, 0, stream>>>(off, bs, cur);

  k_fill<<<(EE + 255) / 256, 256, 0, stream>>>(pos, neg, cur, csrP, csrN);

  k_bw1<<<256, 256, 0, stream>>>(W_in, W1pl, W1pr, W1nl, W1nr, b_in, b1p, b1n, Wcb, bc1);
  k_bw2<<<(384 * HD + 255) / 256, 256, 0, stream>>>(W2pl, W2pr, W2nl, W2nr, b2p, b2n, W2cb, b2c);

  const int gx = (NN + 127) / 128;  // 782
  // G1 = x @ Wc + bc  -> [PA1 | NA1 | R1p | R1n]
  k_mfma<CIN, 2, true><<<dim3(gx, 2), 256, 0, stream>>>(x, Wcb, bc1, G1, NN);

  const int gg = (NN + 3) / 4;  // 25000
  k_gather1<<<gg, 256, 0, stream>>>(G1, off, deg, csrP, z, 0);         // zp
  k_gather1<<<gg, 256, 0, stream>>>(G1, off + NN, deg + NN, csrN, z, 64);  // zn

  // G2 = z @ W2c + b2c -> [PA2 | NA2 | R2]
  k_mfma<HD, 3, false><<<dim3(gx, 3), 256, 0, stream>>>(z, W2cb, b2c, G2, NN);

  k_g2p<<<gg, 256, 0, stream>>>(G2, off, deg, csrP, tmpP);
  k_g2n<<<gg, 256, 0, stream>>>(G2, tmpP, off + NN, deg + NN, csrN, (float*)d_out);
}